// Round 1
// baseline (1847.932 us; speedup 1.0000x reference)
//
#include <hip/hip_runtime.h>

#define SPECIES_CAP 128
// d_ws float layout: [0..3]=a, [4..7]=c(normalized), [8]=p, [9]=d,
// [16..16+SPECIES_CAP)=z_f, [16+SPECIES_CAP .. 16+2*SPECIES_CAP)=z^p*d
#define WS_A   0
#define WS_C   4
#define WS_ZF  16
#define WS_ZPD (16 + SPECIES_CAP)

__global__ void zbl_setup(const float* __restrict__ a_raw,
                          const float* __restrict__ c_raw,
                          const float* __restrict__ p_raw,
                          const float* __restrict__ d_raw,
                          const int* __restrict__ index_to_z,
                          int n_species,
                          float* __restrict__ params)
{
    __shared__ float s_p, s_d;
    int t = threadIdx.x;
    if (t == 0) {
        float a[4], c[4];
        float csum = 0.0f;
        for (int i = 0; i < 4; ++i) {
            a[i] = log1pf(expf(a_raw[i]));          // softplus
            c[i] = log1pf(expf(c_raw[i]));
            csum += c[i];
        }
        for (int i = 0; i < 4; ++i) {
            params[WS_A + i] = a[i];
            params[WS_C + i] = c[i] / csum;
        }
        float p = log1pf(expf(p_raw[0]));
        float d = log1pf(expf(d_raw[0]));
        params[8] = p;
        params[9] = d;
        s_p = p;
        s_d = d;
    }
    __syncthreads();
    float p = s_p, d = s_d;
    for (int s = t; s < n_species && s < SPECIES_CAP; s += blockDim.x) {
        float z = (float)index_to_z[s];
        params[WS_ZF + s]  = z;
        params[WS_ZPD + s] = powf(z, p) * d;        // fold d into the table
    }
}

__device__ __forceinline__ void zbl_edge(
    float dist, float cut, int snd, int rcv,
    const int* __restrict__ node_species,
    const float* s_zf, const float* s_zpd,
    const float* s_a, const float* s_c,
    float* __restrict__ out)
{
    int si = node_species[rcv];
    int sj = node_species[snd];
    float zi = s_zf[si];
    float zj = s_zf[sj];
    float x = cut * zi * zj / (dist + 1e-8f);
    float rzd = dist * (s_zpd[si] + s_zpd[sj]);     // dist*(zi^p+zj^p)*d
    float y = s_c[0] * __expf(-s_a[0] * rzd)
            + s_c[1] * __expf(-s_a[1] * rzd)
            + s_c[2] * __expf(-s_a[2] * rzd)
            + s_c[3] * __expf(-s_a[3] * rzd);
    float sd = dist * (1.0f / 1.5f);
    float u1 = (sd > 1e-8f) ? sd : 1e-8f;
    float u2 = ((1.0f - sd) > 1e-8f) ? (1.0f - sd) : 1e-8f;
    float e_d  = __expf(-1.0f / u1);
    float e_1d = __expf(-1.0f / u2);
    float w = e_1d / (e_1d + e_d);
    // KE/2 folded into the final scale
    float energy = 7.199822675975274f * w * x * y;
    atomicAdd(out + rcv, energy);
}

__global__ __launch_bounds__(256) void zbl_edge_kernel(
    const float* __restrict__ distances,
    const float* __restrict__ cutoffs,
    const int* __restrict__ senders,
    const int* __restrict__ receivers,
    const int* __restrict__ node_species,
    const float* __restrict__ params,
    float* __restrict__ out,
    int E, int n_species)
{
    __shared__ float s_zf[SPECIES_CAP];
    __shared__ float s_zpd[SPECIES_CAP];
    __shared__ float s_a[4];
    __shared__ float s_c[4];
    int t = threadIdx.x;
    if (t < 4)              s_a[t]     = params[WS_A + t];
    else if (t < 8)         s_c[t - 4] = params[WS_C + (t - 4)];
    for (int s = t; s < SPECIES_CAP; s += blockDim.x) {
        // safe to read full cap; only [0,n_species) is ever indexed
        s_zf[s]  = params[WS_ZF + s];
        s_zpd[s] = params[WS_ZPD + s];
    }
    __syncthreads();

    int base = (blockIdx.x * 256 + t) * 4;
    if (base + 4 <= E) {
        float4 d4 = *(const float4*)(distances + base);
        float4 c4 = *(const float4*)(cutoffs + base);
        int4   s4 = *(const int4*)(senders + base);
        int4   r4 = *(const int4*)(receivers + base);
        zbl_edge(d4.x, c4.x, s4.x, r4.x, node_species, s_zf, s_zpd, s_a, s_c, out);
        zbl_edge(d4.y, c4.y, s4.y, r4.y, node_species, s_zf, s_zpd, s_a, s_c, out);
        zbl_edge(d4.z, c4.z, s4.z, r4.z, node_species, s_zf, s_zpd, s_a, s_c, out);
        zbl_edge(d4.w, c4.w, s4.w, r4.w, node_species, s_zf, s_zpd, s_a, s_c, out);
    } else {
        for (int e = base; e < E; ++e) {
            zbl_edge(distances[e], cutoffs[e], senders[e], receivers[e],
                     node_species, s_zf, s_zpd, s_a, s_c, out);
        }
    }
}

extern "C" void kernel_launch(void* const* d_in, const int* in_sizes, int n_in,
                              void* d_out, int out_size, void* d_ws, size_t ws_size,
                              hipStream_t stream)
{
    const int*   node_species = (const int*)d_in[0];
    const float* distances    = (const float*)d_in[1];
    const float* cutoffs      = (const float*)d_in[2];
    const int*   senders      = (const int*)d_in[3];
    const int*   receivers    = (const int*)d_in[4];
    const int*   index_to_z   = (const int*)d_in[5];
    const float* a_raw        = (const float*)d_in[6];
    const float* c_raw        = (const float*)d_in[7];
    const float* p_raw        = (const float*)d_in[8];
    const float* d_raw        = (const float*)d_in[9];

    int E = in_sizes[1];
    int n_species = in_sizes[5];
    float* out    = (float*)d_out;
    float* params = (float*)d_ws;

    // Output must be zeroed every call (harness poisons it with 0xAA).
    hipMemsetAsync(d_out, 0, (size_t)out_size * sizeof(float), stream);

    zbl_setup<<<1, 128, 0, stream>>>(a_raw, c_raw, p_raw, d_raw,
                                     index_to_z, n_species, params);

    int nvec   = (E + 3) / 4;
    int blocks = (nvec + 255) / 256;
    zbl_edge_kernel<<<blocks, 256, 0, stream>>>(
        distances, cutoffs, senders, receivers, node_species,
        params, out, E, n_species);
}